// Round 10
// baseline (160.193 us; speedup 1.0000x reference)
//
#include <hip/hip_runtime.h>
#include <cstdint>

#define CIN 96
#define DIN 96
#define DTR 8
#define DST 16
#define HH 128
#define WW 128
#define HW (HH*WW)
#define NPIX (2*HW)       // B=2
#define DIAG (WW+1)       // diagonal step = 129
#define LOG2E 1.4426950408889634f

__device__ __forceinline__ float softplus_f(float t) {
    return (t > 20.0f) ? t : __logf(1.0f + __expf(t));
}

__device__ __forceinline__ void load_An(const float* __restrict__ AwsT, int d, float* An) {
    float4 A0 = *reinterpret_cast<const float4*>(AwsT + d * 16);
    float4 A1 = *reinterpret_cast<const float4*>(AwsT + d * 16 + 4);
    float4 A2 = *reinterpret_cast<const float4*>(AwsT + d * 16 + 8);
    float4 A3 = *reinterpret_cast<const float4*>(AwsT + d * 16 + 12);
    An[0]=A0.x; An[1]=A0.y; An[2]=A0.z; An[3]=A0.w;
    An[4]=A1.x; An[5]=A1.y; An[6]=A1.z; An[7]=A1.w;
    An[8]=A2.x; An[9]=A2.y; An[10]=A2.z; An[11]=A2.w;
    An[12]=A3.x; An[13]=A3.y; An[14]=A3.z; An[15]=A3.w;
}

// ---------------- Kernel 1: dBC matvec + delta + base output (r6 structure, trimmed) ----------------
// 512 blocks x 512 threads; block = 64 pixels. Wave w computes outputs [5w,5w+5).
__global__ __launch_bounds__(512) void ssm2d_dbc(
    const float* __restrict__ x,
    const float* __restrict__ W1, const float* __restrict__ b1,
    const float* __restrict__ dtw, const float* __restrict__ dtb,
    const float* __restrict__ alog, const float* __restrict__ Dv,
    float* __restrict__ bc, float* __restrict__ cjb, float* __restrict__ kkb,
    float* __restrict__ Aws, float* __restrict__ out)
{
    __shared__ float sX[CIN][65];     // x tile, padded
    __shared__ float sOut[64][41];    // 40 matvec outputs per pixel, padded
    __shared__ float sBC[64];         // dot(B,C) per pixel

    const int t = threadIdx.x;
    const int p0 = blockIdx.x * 64;
    const int bb = p0 >> 14;
    const int q0 = p0 & (HW - 1);
    const float* xb = x + (size_t)bb * CIN * HW + q0;

    #pragma unroll
    for (int it = 0; it < 3; ++it) {
        int i = it * 512 + t;
        int ch = i >> 4;
        int p4 = (i & 15) << 2;
        float4 v = *reinterpret_cast<const float4*>(xb + (size_t)ch * HW + p4);
        sX[ch][p4 + 0] = v.x; sX[ch][p4 + 1] = v.y;
        sX[ch][p4 + 2] = v.z; sX[ch][p4 + 3] = v.w;
    }
    if (blockIdx.x == 0) {   // Aws[d][n] = -exp(A_log[d][n]) * log2(e)
        for (int i = t; i < DIN * DST; i += 512)
            Aws[i] = -__expf(alog[i]) * LOG2E;
    }
    __syncthreads();

    const int lane = t & 63;
    const int w = __builtin_amdgcn_readfirstlane(t >> 6);   // 0..7
    const int og = w * 5;

    float a0 = b1[og + 0], a1 = b1[og + 1], a2 = b1[og + 2],
          a3 = b1[og + 3], a4 = b1[og + 4];
    #pragma unroll 16
    for (int ch = 0; ch < CIN; ++ch) {
        float xv = sX[ch][lane];
        a0 = fmaf(xv, W1[(og + 0) * CIN + ch], a0);
        a1 = fmaf(xv, W1[(og + 1) * CIN + ch], a1);
        a2 = fmaf(xv, W1[(og + 2) * CIN + ch], a2);
        a3 = fmaf(xv, W1[(og + 3) * CIN + ch], a3);
        a4 = fmaf(xv, W1[(og + 4) * CIN + ch], a4);
    }
    sOut[lane][og + 0] = a0; sOut[lane][og + 1] = a1; sOut[lane][og + 2] = a2;
    sOut[lane][og + 3] = a3; sOut[lane][og + 4] = a4;
    __syncthreads();

    if (t < 64) {
        float s = 0.f;
        #pragma unroll
        for (int n = 0; n < DST; ++n) s += sOut[t][8 + n] * sOut[t][24 + n];
        sBC[t] = s;
    }
    __syncthreads();

    // delta + base out + cj pack
    #pragma unroll
    for (int it = 0; it < 12; ++it) {
        int i = it * 512 + t;               // < 6144
        int px = i / 96;
        int d = i - px * 96;
        float tt = dtb[d];
        float4 wA = *reinterpret_cast<const float4*>(dtw + d * DTR);
        float4 wB = *reinterpret_cast<const float4*>(dtw + d * DTR + 4);
        tt = fmaf(sOut[px][0], wA.x, tt); tt = fmaf(sOut[px][1], wA.y, tt);
        tt = fmaf(sOut[px][2], wA.z, tt); tt = fmaf(sOut[px][3], wA.w, tt);
        tt = fmaf(sOut[px][4], wB.x, tt); tt = fmaf(sOut[px][5], wB.y, tt);
        tt = fmaf(sOut[px][6], wB.z, tt); tt = fmaf(sOut[px][7], wB.w, tt);
        float delta = softplus_f(tt);
        float xv = sX[d][px];
        out[(size_t)p0 * 96 + i] = xv * fmaf(delta, sBC[px], Dv[d]);
        cjb[(size_t)p0 * 96 + i] = delta * xv;
    }

    // k writeout (8 rank floats per pixel)
    {
        int px = t >> 3;
        int o = t & 7;
        kkb[(size_t)(p0 + px) * 8 + o] = sOut[px][o];
    }
    // [B|C] writeout
    {
        int px = t >> 3;
        int o4 = (t & 7) << 2;
        float4 v = make_float4(sOut[px][8 + o4], sOut[px][9 + o4],
                               sOut[px][10 + o4], sOut[px][11 + o4]);
        *reinterpret_cast<float4*>(bc + (size_t)(p0 + px) * 32 + o4) = v;
    }
}

// ---------------- Kernel 2: diagonal-local scan. 254 blocks = odd diagonals ----------------
__global__ __launch_bounds__(512) void ssm2d_diag(
    const float* __restrict__ cjb, const float* __restrict__ kkb,
    const float* __restrict__ bcb,
    const float* __restrict__ dtw, const float* __restrict__ dtb,
    const float* __restrict__ Aws, float* __restrict__ out)
{
    __shared__ float sP[128][96];     // delta -> inclusive prefix along j
    __shared__ float sCJ[128][96];    // delta*x
    __shared__ float sB[128][16];
    __shared__ float sC[128][16];
    __shared__ float sTot[8][96];

    const int t = threadIdx.x;
    const int blk = blockIdx.x;            // 0..253
    const int b = (blk >= 127) ? 1 : 0;
    const int kd = blk - b * 127;          // 0..126
    const int k = 2 * kd + 1;              // odd diagonal id, 1..253
    const int r0 = (k > 127) ? (k - 127) : 0;
    const int c0 = (k < 127) ? (127 - k) : 0;
    const int adiff = (k > 127) ? (k - 127) : (127 - k);
    const int dlen = 128 - adiff;          // even, 2..128
    const int p0 = b * HW + r0 * WW + c0;  // pixel j: p0 + j*DIAG

    // load cj + recompute delta
    for (int i = t; i < dlen * 96; i += 512) {
        int j = i / 96;
        int d = i - j * 96;
        size_t pg = (size_t)(p0 + j * DIAG);
        sCJ[j][d] = cjb[pg * 96 + d];
        const float* kr = kkb + pg * 8;
        float4 k0 = *reinterpret_cast<const float4*>(kr);
        float4 k1 = *reinterpret_cast<const float4*>(kr + 4);
        float4 wA = *reinterpret_cast<const float4*>(dtw + d * DTR);
        float4 wB = *reinterpret_cast<const float4*>(dtw + d * DTR + 4);
        float tt = dtb[d];
        tt = fmaf(k0.x, wA.x, tt); tt = fmaf(k0.y, wA.y, tt);
        tt = fmaf(k0.z, wA.z, tt); tt = fmaf(k0.w, wA.w, tt);
        tt = fmaf(k1.x, wB.x, tt); tt = fmaf(k1.y, wB.y, tt);
        tt = fmaf(k1.z, wB.z, tt); tt = fmaf(k1.w, wB.w, tt);
        sP[j][d] = softplus_f(tt);
    }
    // load B, C
    for (int i = t; i < dlen * 16; i += 512) {
        int j = i >> 4;
        int n = i & 15;
        const float* rb = bcb + (size_t)(p0 + j * DIAG) * 32;
        sB[j][n] = rb[n];
        sC[j][n] = rb[16 + n];
    }
    __syncthreads();

    // prefix sum of delta along j (per d): chunked scan
    const int nch = (dlen + 15) >> 4;
    for (int i = t; i < nch * 96; i += 512) {
        int ch = i / 96;
        int d = i - ch * 96;
        float run = 0.f;
        int j0 = ch << 4;
        int j1 = j0 + 16; if (j1 > dlen) j1 = dlen;
        for (int j = j0; j < j1; ++j) { run += sP[j][d]; sP[j][d] = run; }
        sTot[ch][d] = run;
    }
    __syncthreads();
    if (t < 96) {
        float run = 0.f;
        for (int ch = 0; ch < nch; ++ch) {
            float v = sTot[ch][t];
            sTot[ch][t] = run;
            run += v;
        }
    }
    __syncthreads();
    for (int i = t; i < dlen * 96; i += 512) {
        int j = i / 96;
        int d = i - j * 96;
        sP[j][d] += sTot[j >> 4][d];
    }
    __syncthreads();

    // chains: thread per (j, d); all reads from LDS; steps independent via prefix
    for (int i = t; i < dlen * 96; i += 512) {
        int j = i / 96;
        int d = i - j * 96;
        int r = r0 + j, c = c0 + j;
        if (!((r & c) & 1)) continue;       // chains only for odd-odd pixels
        int m = __builtin_ctz(r + 1);
        int mc = __builtin_ctz(c + 1);
        if (mc < m) m = mc;
        int L = 1 << m;                     // 2..128; j >= L-1 guaranteed

        float An[16];
        load_An(Aws, d, An);
        float acc[16];
        #pragma unroll
        for (int n = 0; n < 16; ++n) acc[n] = 0.f;
        float Pj = sP[j][d];
        for (int s = 1; s < L; ++s) {
            int a = j - s;
            float Sv = Pj - sP[a][d];
            float ca = sCJ[a][d];
            #pragma unroll
            for (int n = 0; n < 16; ++n)
                acc[n] = fmaf(exp2f(An[n] * Sv) * sB[a][n], ca, acc[n]);
        }
        float y = 0.f;
        #pragma unroll
        for (int n = 0; n < 16; ++n) y = fmaf(acc[n], sC[j][n], y);
        out[(size_t)(p0 + j * DIAG) * 96 + d] += y;
    }
}

extern "C" void kernel_launch(void* const* d_in, const int* in_sizes, int n_in,
                              void* d_out, int out_size, void* d_ws, size_t ws_size,
                              hipStream_t stream) {
    const float* x    = (const float*)d_in[0];
    const float* W1   = (const float*)d_in[1];
    const float* b1   = (const float*)d_in[2];
    const float* dtw  = (const float*)d_in[3];
    const float* dtb  = (const float*)d_in[4];
    const float* alog = (const float*)d_in[5];
    const float* Dv   = (const float*)d_in[6];
    float* out = (float*)d_out;

    char* ws = (char*)d_ws;
    float* cjb = (float*)(ws);                   // NPIX*96*4 = 12,582,912 B
    float* kkb = (float*)(ws + 12582912);        // NPIX*8*4  =  1,048,576 B
    float* bcb = (float*)(ws + 13631488);        // NPIX*32*4 =  4,194,304 B
    float* Aws = (float*)(ws + 17825792);        // 1536*4

    hipLaunchKernelGGL(ssm2d_dbc, dim3(NPIX / 64), dim3(512), 0, stream,
                       x, W1, b1, dtw, dtb, alog, Dv,
                       bcb, cjb, kkb, Aws, out);
    hipLaunchKernelGGL(ssm2d_diag, dim3(254), dim3(512), 0, stream,
                       cjb, kkb, bcb, dtw, dtb, Aws, out);
}

// Round 11
// 46.434 us; speedup vs baseline: 3.4499x; 3.4499x over previous
//
#include <hip/hip_runtime.h>
#include <cstdint>

#define CIN 96
#define DIN 96
#define DTR 8
#define DST 16
#define HH 128
#define WW 128
#define HW (HH*WW)
#define NPIX (2*HW)       // B=2
#define DIAG (WW+1)       // diagonal step = 129
#define LOG2E 1.4426950408889634f

// scan item space: exact-m sections, 96 d per pixel
#define M1_ITEMS 786432   // 8192 px
#define M2_ITEMS 196608   // 2048 px
#define M3_ITEMS 49152    // 512 px
#define M4_ITEMS 12288    // 128 px
#define M1_BLK 512        // 196608 threads, 4 items each
#define M2_BLK 256        // 98304 threads, 2 items each
#define M3_BLK 128        // 49152 threads, 1 item
#define M4_BLK 32         // 12288 threads, 1 item
#define LONG_BLK 512      // 3072 waves (32 px * 96 d), 6 waves/block
#define SCAN_BLOCKS (M1_BLK + M2_BLK + M3_BLK + M4_BLK + LONG_BLK)

__device__ __forceinline__ float softplus_f(float t) {
    return (t > 20.0f) ? t : __logf(1.0f + __expf(t));
}

__device__ __forceinline__ void load_An(const float* __restrict__ AwsT, int d, float* An) {
    float4 A0 = *reinterpret_cast<const float4*>(AwsT + d * 16);
    float4 A1 = *reinterpret_cast<const float4*>(AwsT + d * 16 + 4);
    float4 A2 = *reinterpret_cast<const float4*>(AwsT + d * 16 + 8);
    float4 A3 = *reinterpret_cast<const float4*>(AwsT + d * 16 + 12);
    An[0]=A0.x; An[1]=A0.y; An[2]=A0.z; An[3]=A0.w;
    An[4]=A1.x; An[5]=A1.y; An[6]=A1.z; An[7]=A1.w;
    An[8]=A2.x; An[9]=A2.y; An[10]=A2.z; An[11]=A2.w;
    An[12]=A3.x; An[13]=A3.y; An[14]=A3.z; An[15]=A3.w;
}

__device__ __forceinline__ float c_dot(const float* __restrict__ rc, const float* acc16) {
    float4 C0 = *reinterpret_cast<const float4*>(rc);
    float4 C1 = *reinterpret_cast<const float4*>(rc + 4);
    float4 C2 = *reinterpret_cast<const float4*>(rc + 8);
    float4 C3 = *reinterpret_cast<const float4*>(rc + 12);
    float ys = 0.f;
    ys = fmaf(acc16[0],C0.x,ys); ys = fmaf(acc16[1],C0.y,ys);
    ys = fmaf(acc16[2],C0.z,ys); ys = fmaf(acc16[3],C0.w,ys);
    ys = fmaf(acc16[4],C1.x,ys); ys = fmaf(acc16[5],C1.y,ys);
    ys = fmaf(acc16[6],C1.z,ys); ys = fmaf(acc16[7],C1.w,ys);
    ys = fmaf(acc16[8],C2.x,ys); ys = fmaf(acc16[9],C2.y,ys);
    ys = fmaf(acc16[10],C2.z,ys); ys = fmaf(acc16[11],C2.w,ys);
    ys = fmaf(acc16[12],C3.x,ys); ys = fmaf(acc16[13],C3.y,ys);
    ys = fmaf(acc16[14],C3.z,ys); ys = fmaf(acc16[15],C3.w,ys);
    return ys;
}

// decode item e (relative to section start) for section M -> (p, d, live)
template<int M>
__device__ __forceinline__ void decode_item(int e, int& p, int& d, bool& live) {
    d = e % 96;
    int pxi = e / 96;
    const int sh = 7 - M;
    const int nM = 1 << sh;
    const int half = nM * nM;
    int img = pxi >= half;
    int e2 = pxi - (img ? half : 0);
    int rr = e2 >> sh;
    int cc = e2 & (nM - 1);
    live = ((rr & cc & 1) == 0);           // exact-m == M
    int r = ((rr + 1) << M) - 1;
    int c = ((cc + 1) << M) - 1;
    p = img * HW + r * WW + c;
}

// compile-time chain, masked contribution via atomicAdd
template<int L>
__device__ __forceinline__ void chain_LT(int p, int d, bool live,
    const float* __restrict__ bc, const float2* __restrict__ dc,
    const float* __restrict__ AwsT, float* __restrict__ out)
{
    size_t base = (size_t)p * 96 + d;
    float2 v0 = dc[base];
    float2 vj[L - 1];
    #pragma unroll
    for (int j = 1; j < L; ++j)
        vj[j - 1] = dc[(size_t)(p - j * DIAG) * 96 + d];
    float An[16];
    load_An(AwsT, d, An);
    float acc16[16];
    #pragma unroll
    for (int n = 0; n < 16; ++n) acc16[n] = 0.f;
    float S = v0.x;
    #pragma unroll
    for (int j = 1; j < L; ++j) {
        const float* rb = bc + (size_t)(p - j * DIAG) * 32;
        float4 B0 = *reinterpret_cast<const float4*>(rb);
        float4 B1 = *reinterpret_cast<const float4*>(rb + 4);
        float4 B2 = *reinterpret_cast<const float4*>(rb + 8);
        float4 B3 = *reinterpret_cast<const float4*>(rb + 12);
        float Bv[16] = {B0.x,B0.y,B0.z,B0.w, B1.x,B1.y,B1.z,B1.w,
                        B2.x,B2.y,B2.z,B2.w, B3.x,B3.y,B3.z,B3.w};
        float cj = vj[j - 1].y;
        #pragma unroll
        for (int n = 0; n < 16; ++n)
            acc16[n] = fmaf(exp2f(An[n] * S) * Bv[n], cj, acc16[n]);
        S += vj[j - 1].x;
    }
    float ys = c_dot(bc + (size_t)p * 32 + 16, acc16);
    if (live) atomicAdd(out + base, ys);
}

// runtime-length chain (m = 3,4)
__device__ __forceinline__ void chain_RT(int p, int d, int L, bool live,
    const float* __restrict__ bc, const float2* __restrict__ dc,
    const float* __restrict__ AwsT, float* __restrict__ out)
{
    size_t base = (size_t)p * 96 + d;
    float An[16];
    load_An(AwsT, d, An);
    float acc16[16];
    #pragma unroll
    for (int n = 0; n < 16; ++n) acc16[n] = 0.f;
    float S = dc[base].x;
    int pj = p;
    for (int j = 1; j < L; ++j) {
        pj -= DIAG;
        float2 v = dc[(size_t)pj * 96 + d];
        const float* rb = bc + (size_t)pj * 32;
        float4 B0 = *reinterpret_cast<const float4*>(rb);
        float4 B1 = *reinterpret_cast<const float4*>(rb + 4);
        float4 B2 = *reinterpret_cast<const float4*>(rb + 8);
        float4 B3 = *reinterpret_cast<const float4*>(rb + 12);
        float Bv[16] = {B0.x,B0.y,B0.z,B0.w, B1.x,B1.y,B1.z,B1.w,
                        B2.x,B2.y,B2.z,B2.w, B3.x,B3.y,B3.z,B3.w};
        #pragma unroll
        for (int n = 0; n < 16; ++n)
            acc16[n] = fmaf(exp2f(An[n] * S) * Bv[n], v.y, acc16[n]);
        S += v.x;
    }
    float ys = c_dot(bc + (size_t)p * 32 + 16, acc16);
    if (live) atomicAdd(out + base, ys);
}

// ---------------- Kernel 1: dBC matvec + delta + base output ----------------
__global__ __launch_bounds__(512) void ssm2d_dbc(
    const float* __restrict__ x,
    const float* __restrict__ W1, const float* __restrict__ b1,
    const float* __restrict__ dtw, const float* __restrict__ dtb,
    const float* __restrict__ alog, const float* __restrict__ Dv,
    float* __restrict__ bc, float2* __restrict__ dc,
    float* __restrict__ Aws, float* __restrict__ out)
{
    __shared__ float sX[CIN][65];
    __shared__ float sOut[64][41];
    __shared__ float sBC[64];

    const int t = threadIdx.x;
    const int p0 = blockIdx.x * 64;
    const int bb = p0 >> 14;
    const int q0 = p0 & (HW - 1);
    const float* xb = x + (size_t)bb * CIN * HW + q0;

    #pragma unroll
    for (int it = 0; it < 3; ++it) {
        int i = it * 512 + t;
        int ch = i >> 4;
        int p4 = (i & 15) << 2;
        float4 v = *reinterpret_cast<const float4*>(xb + (size_t)ch * HW + p4);
        sX[ch][p4 + 0] = v.x; sX[ch][p4 + 1] = v.y;
        sX[ch][p4 + 2] = v.z; sX[ch][p4 + 3] = v.w;
    }
    if (blockIdx.x == 0) {   // Aws[d][n] = -exp(A_log[d][n]) * log2(e)
        for (int i = t; i < DIN * DST; i += 512)
            Aws[i] = -__expf(alog[i]) * LOG2E;
    }
    __syncthreads();

    const int lane = t & 63;
    const int w = __builtin_amdgcn_readfirstlane(t >> 6);   // 0..7
    const int og = w * 5;

    float a0 = b1[og + 0], a1 = b1[og + 1], a2 = b1[og + 2],
          a3 = b1[og + 3], a4 = b1[og + 4];
    #pragma unroll 16
    for (int ch = 0; ch < CIN; ++ch) {
        float xv = sX[ch][lane];
        a0 = fmaf(xv, W1[(og + 0) * CIN + ch], a0);
        a1 = fmaf(xv, W1[(og + 1) * CIN + ch], a1);
        a2 = fmaf(xv, W1[(og + 2) * CIN + ch], a2);
        a3 = fmaf(xv, W1[(og + 3) * CIN + ch], a3);
        a4 = fmaf(xv, W1[(og + 4) * CIN + ch], a4);
    }
    sOut[lane][og + 0] = a0; sOut[lane][og + 1] = a1; sOut[lane][og + 2] = a2;
    sOut[lane][og + 3] = a3; sOut[lane][og + 4] = a4;
    __syncthreads();

    if (t < 64) {
        float s = 0.f;
        #pragma unroll
        for (int n = 0; n < DST; ++n) s += sOut[t][8 + n] * sOut[t][24 + n];
        sBC[t] = s;
    }
    __syncthreads();

    #pragma unroll
    for (int it = 0; it < 12; ++it) {
        int i = it * 512 + t;               // < 6144
        int px = i / 96;
        int d = i - px * 96;
        float tt = dtb[d];
        float4 wA = *reinterpret_cast<const float4*>(dtw + d * DTR);
        float4 wB = *reinterpret_cast<const float4*>(dtw + d * DTR + 4);
        tt = fmaf(sOut[px][0], wA.x, tt); tt = fmaf(sOut[px][1], wA.y, tt);
        tt = fmaf(sOut[px][2], wA.z, tt); tt = fmaf(sOut[px][3], wA.w, tt);
        tt = fmaf(sOut[px][4], wB.x, tt); tt = fmaf(sOut[px][5], wB.y, tt);
        tt = fmaf(sOut[px][6], wB.z, tt); tt = fmaf(sOut[px][7], wB.w, tt);
        float delta = softplus_f(tt);
        float xv = sX[d][px];
        out[(size_t)p0 * 96 + i] = xv * fmaf(delta, sBC[px], Dv[d]);
        dc[(size_t)p0 * 96 + i] = make_float2(delta, delta * xv);
    }

    {
        int px = t >> 3;
        int o4 = (t & 7) << 2;
        float4 v = make_float4(sOut[px][8 + o4], sOut[px][9 + o4],
                               sOut[px][10 + o4], sOut[px][11 + o4]);
        *reinterpret_cast<float4*>(bc + (size_t)(p0 + px) * 32 + o4) = v;
    }
}

// ---------------- Kernel 2: chain contributions, m-partitioned, item-batched ----------------
__global__ __launch_bounds__(384) void ssm2d_scan(
    const float* __restrict__ bc, const float2* __restrict__ dc,
    const float* __restrict__ AwsT, float* __restrict__ out)
{
    const int t = threadIdx.x;
    const int blk = blockIdx.x;

    if (blk < M1_BLK) {
        // M=1 (L=2): 4 independent items per thread, branchless loads
        const int tid = blk * 384 + t;              // < 196608
        #pragma unroll
        for (int k = 0; k < 4; ++k) {
            int e = tid + k * 196608;
            int p, d; bool live;
            decode_item<1>(e, p, d, live);
            chain_LT<2>(p, d, live, bc, dc, AwsT, out);
        }
    } else if (blk < M1_BLK + M2_BLK) {
        // M=2 (L=4): 2 items per thread
        const int tid = (blk - M1_BLK) * 384 + t;   // < 98304
        #pragma unroll
        for (int k = 0; k < 2; ++k) {
            int e = tid + k * 98304;
            int p, d; bool live;
            decode_item<2>(e, p, d, live);
            chain_LT<4>(p, d, live, bc, dc, AwsT, out);
        }
    } else if (blk < M1_BLK + M2_BLK + M3_BLK) {
        // M=3 (L=8)
        const int e = (blk - M1_BLK - M2_BLK) * 384 + t;   // < 49152
        int p, d; bool live;
        decode_item<3>(e, p, d, live);
        chain_RT(p, d, 8, live, bc, dc, AwsT, out);
    } else if (blk < M1_BLK + M2_BLK + M3_BLK + M4_BLK) {
        // M=4 (L=16)
        const int e = (blk - M1_BLK - M2_BLK - M3_BLK) * 384 + t;  // < 12288
        int p, d; bool live;
        decode_item<4>(e, p, d, live);
        chain_RT(p, d, 16, live, bc, dc, AwsT, out);
    } else {
        // long chains (m >= 5): one wave per (pixel, d), lane-parallel over j
        const int wv = t >> 6;
        const int lane = t & 63;
        int waveid = (blk - (M1_BLK + M2_BLK + M3_BLK + M4_BLK)) * 6 + wv;  // 0..3071
        int pix = waveid / DIN;          // 0..31
        int d = waveid - pix * DIN;
        int batch = pix >> 4;
        int sel = pix & 15;
        int r = ((sel >> 2) + 1) * 32 - 1;   // 31,63,95,127
        int c = ((sel & 3) + 1) * 32 - 1;
        int p = batch * HW + r * WW + c;
        int m = __builtin_ctz(r + 1);
        int mc = __builtin_ctz(c + 1);
        if (mc < m) m = mc;
        int L = 1 << m;                      // 32, 64, or 128

        float An[16];
        load_An(AwsT, d, An);

        float acc16[16];
        #pragma unroll
        for (int n = 0; n < 16; ++n) acc16[n] = 0.0f;
        float Scarry = 0.0f;

        for (int jb = 0; jb < L; jb += 64) {
            int j = jb + lane;
            bool act = (j < L);
            int jc = act ? j : 0;
            int pj = p - DIAG * jc;
            float2 v = dc[(size_t)pj * 96 + d];
            float dj = act ? v.x : 0.0f;
            float cj = (j >= 1 && act) ? v.y : 0.0f;   // j=0 term already in out

            float incl = dj;
            #pragma unroll
            for (int off = 1; off < 64; off <<= 1) {
                float u = __shfl_up(incl, off);
                if (lane >= off) incl += u;
            }
            float S = Scarry + incl - dj;

            const float* rb = bc + (size_t)pj * 32;
            float4 B0 = *reinterpret_cast<const float4*>(rb);
            float4 B1 = *reinterpret_cast<const float4*>(rb + 4);
            float4 B2 = *reinterpret_cast<const float4*>(rb + 8);
            float4 B3 = *reinterpret_cast<const float4*>(rb + 12);
            float Bv[16] = {B0.x,B0.y,B0.z,B0.w, B1.x,B1.y,B1.z,B1.w,
                            B2.x,B2.y,B2.z,B2.w, B3.x,B3.y,B3.z,B3.w};
            #pragma unroll
            for (int n = 0; n < 16; ++n)
                acc16[n] = fmaf(exp2f(An[n] * S) * Bv[n], cj, acc16[n]);

            Scarry += __shfl(incl, 63);
        }

        #pragma unroll
        for (int off = 32; off >= 1; off >>= 1) {
            #pragma unroll
            for (int n = 0; n < 16; ++n) acc16[n] += __shfl_xor(acc16[n], off);
        }

        if (lane == 0) {
            float y = c_dot(bc + (size_t)p * 32 + 16, acc16);
            atomicAdd(out + (size_t)p * 96 + d, y);
        }
    }
}

extern "C" void kernel_launch(void* const* d_in, const int* in_sizes, int n_in,
                              void* d_out, int out_size, void* d_ws, size_t ws_size,
                              hipStream_t stream) {
    const float* x    = (const float*)d_in[0];
    const float* W1   = (const float*)d_in[1];
    const float* b1   = (const float*)d_in[2];
    const float* dtw  = (const float*)d_in[3];
    const float* dtb  = (const float*)d_in[4];
    const float* alog = (const float*)d_in[5];
    const float* Dv   = (const float*)d_in[6];
    float* out = (float*)d_out;

    char* ws = (char*)d_ws;
    float2* dc  = (float2*)(ws);                 // NPIX*96*8 = 25,165,824 B
    float*  bcb = (float*)(ws + 25165824);       // NPIX*32*4 =  4,194,304 B
    float*  Aws = (float*)(ws + 29360128);       // 1536*4

    hipLaunchKernelGGL(ssm2d_dbc, dim3(NPIX / 64), dim3(512), 0, stream,
                       x, W1, b1, dtw, dtb, alog, Dv,
                       bcb, dc, Aws, out);
    hipLaunchKernelGGL(ssm2d_scan, dim3(SCAN_BLOCKS), dim3(384), 0, stream,
                       bcb, dc, Aws, out);
}